// Round 1
// baseline (194.068 us; speedup 1.0000x reference)
//
#include <hip/hip_runtime.h>
#include <math.h>

// Problem shape (fixed by setup_inputs): x (32,1024,1024) f32, weight (1024,1024) f32,
// bias (1024,) f32, out (32,1,1024) f32.
//
// Semantics: fix_x(x) = clamp(floor(32x)/32, -127/32, 127/32). All post-fix values are
// k/32 with k in [-127,127] -> exact integer domain. The scan is a saturating integer
// fold, parallelized via the clamped-shift-function monoid:
//   f(a)=clamp(a+s,L,U);  (G∘F) = (sF+sG, clamp(LF+sG,LG,UG), clamp(UF+sG,LG,UG))
// init folds in as constant fn (0,v,v) so the total composition has L==U==acc.

#define IN_DIM  1024
#define OUT_DIM 1024
#define B_DIM   32

__global__ __launch_bounds__(256) void ffl_kernel(
    const float* __restrict__ x,
    const float* __restrict__ w,
    const float* __restrict__ bias,
    float* __restrict__ out)
{
    const int lane = threadIdx.x & 63;
    const int wid  = threadIdx.x >> 6;

    // pair index p = o*32 + b : 4 waves of a block share one weight row o
    const int o = blockIdx.x >> 3;                 // 8 blocks per o
    const int b = ((blockIdx.x & 7) << 2) | wid;   // 8*4 = 32 b-values

    const float4* xp = (const float4*)(x + ((size_t)b * OUT_DIM + o) * IN_DIM + lane * 16);
    const float4* wp = (const float4*)(w + (size_t)o * IN_DIM + lane * 16);

    // running composed function (identity), built over this lane's 16 contiguous elems
    int rs = 0;
    int rL = -(1 << 28);
    int rU =  (1 << 28);

    #pragma unroll
    for (int j = 0; j < 4; ++j) {
        float4 xv = xp[j];
        float4 wv = wp[j];
        float pe[4] = { xv.x * wv.x, xv.y * wv.y, xv.z * wv.z, xv.w * wv.w };
        #pragma unroll
        for (int e = 0; e < 4; ++e) {
            // quantize: v = clamp(floor(32 * (x*w)), -127, 127)
            // NOTE: (x*w) rounds first (matches JAX), *32 is exact (power of 2)
            float t = pe[e] * 32.0f;
            int v = (int)floorf(t);
            v = min(max(v, -127), 127);
            // element i=1023 is the scan init -> constant function (0, v, v)
            bool isInit = (j == 3) && (e == 3) && (lane == 63);
            int sE = isInit ? 0 : v;
            int LE = isInit ? v : -127;
            int UE = isInit ? v : 127;
            // new = running ∘ elem  (running outer: lower index applied later)
            int ns = sE + rs;
            int nL = min(max(LE + rs, rL), rU);
            int nU = min(max(UE + rs, rL), rU);
            rs = ns; rL = nL; rU = nU;
        }
    }

    // 6-step butterfly: lane with lower block index is the OUTER function.
    // After the loop every lane holds the total composition; since the constant
    // init function is innermost, L == U == acc.
    #pragma unroll
    for (int m = 1; m < 64; m <<= 1) {
        int ps = __shfl_xor(rs, m, 64);
        int pL = __shfl_xor(rL, m, 64);
        int pU = __shfl_xor(rU, m, 64);
        bool lower = ((lane & m) == 0);
        int sG = lower ? rs : ps;   // outer
        int LG = lower ? rL : pL;
        int UG = lower ? rU : pU;
        int sF = lower ? ps : rs;   // inner
        int LF = lower ? pL : rL;
        int UF = lower ? pU : rU;
        rs = sF + sG;
        rL = min(max(LF + sG, LG), UG);
        rU = min(max(UF + sG, LG), UG);
    }

    if (lane == 0) {
        // acc (= rL = rU) is exact; final: fix_x(acc/32 + bias) in fp32 like the ref
        float acc = (float)rL * 0.03125f;          // exact (power of 2)
        float tb  = acc + bias[o];                 // single fp32 rounding, matches ref
        float r   = floorf(tb * 32.0f);            // *32 exact
        r = fminf(fmaxf(r, -127.0f), 127.0f);
        out[(size_t)b * OUT_DIM + o] = r * 0.03125f;
    }
}

extern "C" void kernel_launch(void* const* d_in, const int* in_sizes, int n_in,
                              void* d_out, int out_size, void* d_ws, size_t ws_size,
                              hipStream_t stream) {
    const float* x    = (const float*)d_in[0];
    const float* w    = (const float*)d_in[1];
    const float* bias = (const float*)d_in[2];
    float* out = (float*)d_out;

    const int pairs  = B_DIM * OUT_DIM;    // 32768 (b,o) pairs, one wave each
    const int blocks = pairs / 4;          // 4 waves per 256-thread block
    ffl_kernel<<<blocks, 256, 0, stream>>>(x, w, bias, out);
}